// Round 2
// baseline (478.185 us; speedup 1.0000x reference)
//
#include <hip/hip_runtime.h>
#include <math.h>

#define B_      64
#define N_      153600      // C*H*W = 8*120*160
#define BPB     32          // blocks per batch
#define THREADS 256

typedef float vf4 __attribute__((ext_vector_type(4)));

// d_ws layout: [0,256)   : int counters[64] (zeroed via hipMemsetAsync each call)
//              [256,...) : float partial[B][BPB][6]
#define CNT_BYTES 256

__device__ __forceinline__ void solve_one(
    int b, const float* __restrict__ sums,
    const float* __restrict__ JtJ, const float* __restrict__ poseR,
    const float* __restrict__ poseT, float* __restrict__ out)
{
    // Hessian = JtJ + trace(JtJ)*1e-6 * I ; solve H xi = JtR
    const float* Hj = JtJ + (size_t)b * 36;
    const float tr = Hj[0] + Hj[7] + Hj[14] + Hj[21] + Hj[28] + Hj[35];
    float M[6][7];
#pragma unroll
    for (int i = 0; i < 6; ++i) {
#pragma unroll
        for (int j = 0; j < 6; ++j) M[i][j] = Hj[i * 6 + j];
        M[i][i] += tr * 1e-6f;
        M[i][6] = sums[i];
    }
    // Gaussian elimination with partial pivoting (H is SPD-damped; well conditioned)
    for (int col = 0; col < 6; ++col) {
        int piv = col; float best = fabsf(M[col][col]);
        for (int r = col + 1; r < 6; ++r) {
            float a = fabsf(M[r][col]);
            if (a > best) { best = a; piv = r; }
        }
        if (piv != col)
            for (int j = col; j < 7; ++j) { float t = M[col][j]; M[col][j] = M[piv][j]; M[piv][j] = t; }
        const float inv = 1.0f / M[col][col];
        for (int r = col + 1; r < 6; ++r) {
            const float f = M[r][col] * inv;
            for (int j = col; j < 7; ++j) M[r][j] -= f * M[col][j];
        }
    }
    float xi[6];
    for (int i = 5; i >= 0; --i) {
        float s = M[i][6];
        for (int j = i + 1; j < 6; ++j) s -= M[i][j] * xi[j];
        xi[i] = s / M[i][i];
    }

    // dR = twist2mat(-xi[:3]) = c*I + (1-c)*u u^T + s*K(u)
    const float wx = -xi[0], wy = -xi[1], wz = -xi[2];
    float th = sqrtf(wx * wx + wy * wy + wz * wz);
    th = fmaxf(th, 1e-12f);
    const float ux = wx / th, uy = wy / th, uz = wz / th;
    const float s = sinf(th), c = cosf(th), omc = 1.0f - c;
    float dR[3][3];
    dR[0][0] = c + omc * ux * ux;       dR[0][1] = omc * ux * uy - s * uz;  dR[0][2] = omc * ux * uz + s * uy;
    dR[1][0] = omc * uy * ux + s * uz;  dR[1][1] = c + omc * uy * uy;       dR[1][2] = omc * uy * uz - s * ux;
    dR[2][0] = omc * uz * ux - s * uy;  dR[2][1] = omc * uz * uy + s * ux;  dR[2][2] = c + omc * uz * uz;

    // dt = -(dR @ xi[3:])
    float dt[3];
#pragma unroll
    for (int i = 0; i < 3; ++i)
        dt[i] = -(dR[i][0] * xi[3] + dR[i][1] * xi[4] + dR[i][2] * xi[5]);

    // R_new = pose_R @ dR ; t_new = pose_R @ dt + pose_t
    const float* pR = poseR + (size_t)b * 9;
#pragma unroll
    for (int i = 0; i < 3; ++i) {
        const float p0 = pR[i * 3 + 0], p1 = pR[i * 3 + 1], p2 = pR[i * 3 + 2];
#pragma unroll
        for (int j = 0; j < 3; ++j)
            out[b * 9 + i * 3 + j] = p0 * dR[0][j] + p1 * dR[1][j] + p2 * dR[2][j];
        out[B_ * 9 + b * 3 + i] = p0 * dt[0] + p1 * dt[1] + p2 * dt[2] + poseT[b * 3 + i];
    }
}

__global__ __launch_bounds__(THREADS) void fused_kernel(
    const float* __restrict__ Jt,     // (B, 6, N)
    const float* __restrict__ W,      // (B, N)
    const float* __restrict__ R,      // (B, N)
    const float* __restrict__ JtJ,    // (B, 6, 6)
    const float* __restrict__ poseR,  // (B, 3, 3)
    const float* __restrict__ poseT,  // (B, 3)
    float* __restrict__ out,          // R_new (B*9) then t_new (B*3)
    float* __restrict__ partial,      // (B, BPB, 6)
    int* __restrict__ counters)       // (B,) pre-zeroed
{
    const int b   = blockIdx.x / BPB;
    const int blk = blockIdx.x % BPB;
    const int tid = threadIdx.x;

    const vf4* w4 = (const vf4*)(W + (size_t)b * N_);
    const vf4* r4 = (const vf4*)(R + (size_t)b * N_);
    const float* jt = Jt + (size_t)b * 6 * N_;
    const int n4    = N_ / 4;        // 38400 float4 per stream per batch
    const int chunk = n4 / BPB;      // 1200, contiguous per block
    const int i0    = blk * chunk;

    float acc[6] = {0.f, 0.f, 0.f, 0.f, 0.f, 0.f};
    for (int i = i0 + tid; i < i0 + chunk; i += THREADS) {
        vf4 wv = __builtin_nontemporal_load(&w4[i]);
        vf4 rv = __builtin_nontemporal_load(&r4[i]);
        const float wr0 = wv.x * rv.x, wr1 = wv.y * rv.y;
        const float wr2 = wv.z * rv.z, wr3 = wv.w * rv.w;
#pragma unroll
        for (int k = 0; k < 6; ++k) {
            vf4 jv = __builtin_nontemporal_load((const vf4*)(jt + (size_t)k * N_) + i);
            acc[k] += jv.x * wr0 + jv.y * wr1 + jv.z * wr2 + jv.w * wr3;
        }
    }

    // wave (64-lane) reduction of the 6 accumulators
#pragma unroll
    for (int k = 0; k < 6; ++k) {
        float v = acc[k];
#pragma unroll
        for (int off = 32; off >= 1; off >>= 1) v += __shfl_down(v, off, 64);
        acc[k] = v;
    }

    __shared__ float smem[4][6];
    __shared__ int lastFlag;
    const int lane = tid & 63;
    const int wid  = tid >> 6;
    if (lane == 0) {
#pragma unroll
        for (int k = 0; k < 6; ++k) smem[wid][k] = acc[k];
    }
    __syncthreads();
    if (tid < 6) {
        float s = smem[0][tid] + smem[1][tid] + smem[2][tid] + smem[3][tid];
        partial[(size_t)(b * BPB + blk) * 6 + tid] = s;
    }
    __syncthreads();          // partial stores done block-wide
    __threadfence();          // release to device scope (agent fence; flushes L2)
    if (tid == 0) {
        int old = atomicAdd(&counters[b], 1);   // device-scope by default
        lastFlag = (old == BPB - 1);
    }
    __syncthreads();

    if (lastFlag) {
        __threadfence();      // acquire: invalidate stale caches before reading partials
        __shared__ float sums[6];
        if (tid < 6) {
            float s = 0.f;
            const float* p = partial + (size_t)b * BPB * 6 + tid;
#pragma unroll
            for (int j = 0; j < BPB; ++j)
                s += __hip_atomic_load(p + j * 6, __ATOMIC_RELAXED, __HIP_MEMORY_SCOPE_AGENT);
            sums[tid] = s;
        }
        __syncthreads();
        if (tid == 0)
            solve_one(b, sums, JtJ, poseR, poseT, out);
    }
}

extern "C" void kernel_launch(void* const* d_in, const int* in_sizes, int n_in,
                              void* d_out, int out_size, void* d_ws, size_t ws_size,
                              hipStream_t stream) {
    const float* JtJ     = (const float*)d_in[0];
    const float* Jt      = (const float*)d_in[1];
    const float* weights = (const float*)d_in[2];
    const float* R       = (const float*)d_in[3];
    const float* pose_R  = (const float*)d_in[4];
    const float* pose_t  = (const float*)d_in[5];
    // d_in[6..10] (invD0, invD1, x0, x1, K) are unused by the reference.

    int*   counters = (int*)d_ws;
    float* partial  = (float*)((char*)d_ws + CNT_BYTES);
    float* out      = (float*)d_out;

    // Counters must be 0 at kernel start on every call (graph replays included;
    // d_ws is poisoned to 0xAA once before timing). Async memset is capture-safe.
    hipMemsetAsync(counters, 0, B_ * sizeof(int), stream);

    fused_kernel<<<B_ * BPB, THREADS, 0, stream>>>(
        Jt, weights, R, JtJ, pose_R, pose_t, out, partial, counters);
}

// Round 3
// 59.459 us; speedup vs baseline: 8.0422x; 8.0422x over previous
//
#include <hip/hip_runtime.h>
#include <math.h>

#define B_      64
#define N_      153600      // C*H*W = 8*120*160
#define BPB     30          // blocks per batch: 38400 float4 / 30 = 1280 / 256 thr = 5 iters exact
#define THREADS 256
#define CHUNK   (N_ / 4 / BPB)   // 1280 float4 per block
#define ITERS   (CHUNK / THREADS) // 5

typedef float vf4 __attribute__((ext_vector_type(4)));

// Stage 1: partial[b, blk, k] = sum over this block's contiguous chunk of
//          Jt[b,k,n] * w[b,n] * r[b,n]
__global__ __launch_bounds__(THREADS) void jtr_partial_kernel(
    const float* __restrict__ Jt,     // (B, 6, N)
    const float* __restrict__ W,      // (B, N)
    const float* __restrict__ R,      // (B, N)
    float* __restrict__ partial)      // (B, BPB, 6)
{
    const int b   = blockIdx.x / BPB;
    const int blk = blockIdx.x % BPB;
    const int tid = threadIdx.x;

    const vf4* w4 = (const vf4*)(W + (size_t)b * N_);
    const vf4* r4 = (const vf4*)(R + (size_t)b * N_);
    const float* jt = Jt + (size_t)b * 6 * N_;
    const int i0 = blk * CHUNK + tid;

    float acc[6] = {0.f, 0.f, 0.f, 0.f, 0.f, 0.f};
#pragma unroll
    for (int j = 0; j < ITERS; ++j) {
        const int i = i0 + j * THREADS;
        vf4 wv = w4[i];
        vf4 rv = r4[i];
        const float wr0 = wv.x * rv.x, wr1 = wv.y * rv.y;
        const float wr2 = wv.z * rv.z, wr3 = wv.w * rv.w;
#pragma unroll
        for (int k = 0; k < 6; ++k) {
            vf4 jv = ((const vf4*)(jt + (size_t)k * N_))[i];
            acc[k] += jv.x * wr0 + jv.y * wr1 + jv.z * wr2 + jv.w * wr3;
        }
    }

    // 64-lane wave reduction of the 6 accumulators
#pragma unroll
    for (int k = 0; k < 6; ++k) {
        float v = acc[k];
#pragma unroll
        for (int off = 32; off >= 1; off >>= 1) v += __shfl_down(v, off, 64);
        acc[k] = v;
    }

    __shared__ float smem[4][6];
    const int lane = tid & 63;
    const int wid  = tid >> 6;
    if (lane == 0) {
#pragma unroll
        for (int k = 0; k < 6; ++k) smem[wid][k] = acc[k];
    }
    __syncthreads();
    if (tid < 6) {
        partial[(size_t)(b * BPB + blk) * 6 + tid] =
            smem[0][tid] + smem[1][tid] + smem[2][tid] + smem[3][tid];
    }
}

// Stage 2: one block per batch. Threads 0..5 reduce the 30 partials for their
// component (loads pipeline — independent addresses); thread 0 runs the tiny
// 6x6 damped solve + Rodrigues + pose compose.
__global__ __launch_bounds__(64) void solve_kernel(
    const float* __restrict__ partial,   // (B, BPB, 6)
    const float* __restrict__ JtJ,       // (B, 6, 6)
    const float* __restrict__ poseR,     // (B, 3, 3)
    const float* __restrict__ poseT,     // (B, 3)
    float* __restrict__ out)             // R_new (B*9) then t_new (B*3)
{
    const int b = blockIdx.x;
    const int t = threadIdx.x;

    __shared__ float sums[6];
    if (t < 6) {
        const float* p = partial + (size_t)b * BPB * 6 + t;
        float s = 0.f;
#pragma unroll
        for (int j = 0; j < BPB; ++j) s += p[j * 6];
        sums[t] = s;
    }
    __syncthreads();
    if (t != 0) return;

    // Hessian = JtJ + trace(JtJ)*1e-6 * I ; solve H xi = JtR
    const float* Hj = JtJ + (size_t)b * 36;
    const float tr = Hj[0] + Hj[7] + Hj[14] + Hj[21] + Hj[28] + Hj[35];
    float M[6][7];
#pragma unroll
    for (int i = 0; i < 6; ++i) {
#pragma unroll
        for (int j = 0; j < 6; ++j) M[i][j] = Hj[i * 6 + j];
        M[i][i] += tr * 1e-6f;
        M[i][6] = sums[i];
    }
    for (int col = 0; col < 6; ++col) {
        int piv = col; float best = fabsf(M[col][col]);
        for (int r = col + 1; r < 6; ++r) {
            float a = fabsf(M[r][col]);
            if (a > best) { best = a; piv = r; }
        }
        if (piv != col)
            for (int j = col; j < 7; ++j) { float tm = M[col][j]; M[col][j] = M[piv][j]; M[piv][j] = tm; }
        const float inv = 1.0f / M[col][col];
        for (int r = col + 1; r < 6; ++r) {
            const float f = M[r][col] * inv;
            for (int j = col; j < 7; ++j) M[r][j] -= f * M[col][j];
        }
    }
    float xi[6];
    for (int i = 5; i >= 0; --i) {
        float s = M[i][6];
        for (int j = i + 1; j < 6; ++j) s -= M[i][j] * xi[j];
        xi[i] = s / M[i][i];
    }

    // dR = twist2mat(-xi[:3]) = c*I + (1-c)*u u^T + s*K(u)
    const float wx = -xi[0], wy = -xi[1], wz = -xi[2];
    float th = fmaxf(sqrtf(wx * wx + wy * wy + wz * wz), 1e-12f);
    const float ux = wx / th, uy = wy / th, uz = wz / th;
    const float s = sinf(th), c = cosf(th), omc = 1.0f - c;
    float dR[3][3];
    dR[0][0] = c + omc * ux * ux;       dR[0][1] = omc * ux * uy - s * uz;  dR[0][2] = omc * ux * uz + s * uy;
    dR[1][0] = omc * uy * ux + s * uz;  dR[1][1] = c + omc * uy * uy;       dR[1][2] = omc * uy * uz - s * ux;
    dR[2][0] = omc * uz * ux - s * uy;  dR[2][1] = omc * uz * uy + s * ux;  dR[2][2] = c + omc * uz * uz;

    // dt = -(dR @ xi[3:])
    float dt[3];
#pragma unroll
    for (int i = 0; i < 3; ++i)
        dt[i] = -(dR[i][0] * xi[3] + dR[i][1] * xi[4] + dR[i][2] * xi[5]);

    // R_new = pose_R @ dR ; t_new = pose_R @ dt + pose_t
    const float* pR = poseR + (size_t)b * 9;
#pragma unroll
    for (int i = 0; i < 3; ++i) {
        const float p0 = pR[i * 3 + 0], p1 = pR[i * 3 + 1], p2 = pR[i * 3 + 2];
#pragma unroll
        for (int j = 0; j < 3; ++j)
            out[b * 9 + i * 3 + j] = p0 * dR[0][j] + p1 * dR[1][j] + p2 * dR[2][j];
        out[B_ * 9 + b * 3 + i] = p0 * dt[0] + p1 * dt[1] + p2 * dt[2] + poseT[b * 3 + i];
    }
}

extern "C" void kernel_launch(void* const* d_in, const int* in_sizes, int n_in,
                              void* d_out, int out_size, void* d_ws, size_t ws_size,
                              hipStream_t stream) {
    const float* JtJ     = (const float*)d_in[0];
    const float* Jt      = (const float*)d_in[1];
    const float* weights = (const float*)d_in[2];
    const float* R       = (const float*)d_in[3];
    const float* pose_R  = (const float*)d_in[4];
    const float* pose_t  = (const float*)d_in[5];
    // d_in[6..10] (invD0, invD1, x0, x1, K) unused by the reference.

    float* out     = (float*)d_out;
    float* partial = (float*)d_ws;   // B*BPB*6 floats = 45 KB

    jtr_partial_kernel<<<B_ * BPB, THREADS, 0, stream>>>(Jt, weights, R, partial);
    solve_kernel<<<B_, 64, 0, stream>>>(partial, JtJ, pose_R, pose_t, out);
}